// Round 1
// baseline (244.473 us; speedup 1.0000x reference)
//
#include <hip/hip_runtime.h>

typedef unsigned short u16;
typedef unsigned int u32;
typedef __attribute__((ext_vector_type(8))) short s16x8;
typedef __attribute__((ext_vector_type(4))) float f32x4;

#define NB 2
#define NH 16
#define NS 2048
#define ND 1024

__device__ __forceinline__ u16 f2bf(float f) {
  u32 u = __float_as_uint(f);
  u = u + 0x7FFFu + ((u >> 16) & 1u);
  return (u16)(u >> 16);
}

// ---------------------------------------------------------------------------
// QKV projection: X[4096,1024] @ W^T + b.
// which=0 (q) / 1 (k): write head-split bf16 [B,H,S,64]
// which=2 (v):         write transposed bf16 [B,H,64,S]
// ---------------------------------------------------------------------------
__global__ __launch_bounds__(256) void proj_qkv_kernel(
    const float* __restrict__ Qin, const float* __restrict__ Kin,
    const float* __restrict__ Vin,
    const float* __restrict__ Wq, const float* __restrict__ bq,
    const float* __restrict__ Wk, const float* __restrict__ bk,
    const float* __restrict__ Wv, const float* __restrict__ bv,
    u16* __restrict__ qh, u16* __restrict__ kh, u16* __restrict__ vT) {
  const int which = blockIdx.z;
  const float* X = (which == 0) ? Qin : (which == 1) ? Kin : Vin;
  const float* W = (which == 0) ? Wq : (which == 1) ? Wk : Wv;
  const float* bias = (which == 0) ? bq : (which == 1) ? bk : bv;

  const int m0 = blockIdx.y * 128, n0 = blockIdx.x * 128;
  const int tid = threadIdx.x;
  const int w = tid >> 6, l = tid & 63, lr = l & 15, lg = l >> 4;
  const int wr = (w >> 1) * 64, wc = (w & 1) * 64;

  __shared__ u16 As[128][40];  // +8 pad breaks pow2 bank stride
  __shared__ u16 Bs[128][40];

  const f32x4 fzero = {0.f, 0.f, 0.f, 0.f};
  f32x4 acc[4][4];
#pragma unroll
  for (int m = 0; m < 4; ++m)
#pragma unroll
    for (int n = 0; n < 4; ++n) acc[m][n] = fzero;

  for (int k0 = 0; k0 < 1024; k0 += 32) {
#pragma unroll
    for (int i = 0; i < 4; ++i) {
      int idx = tid + i * 256;
      int row = idx >> 3, c4 = (idx & 7) * 4;
      float4 a = *(const float4*)(X + (size_t)(m0 + row) * 1024 + k0 + c4);
      *(u32*)&As[row][c4]     = (u32)f2bf(a.x) | ((u32)f2bf(a.y) << 16);
      *(u32*)&As[row][c4 + 2] = (u32)f2bf(a.z) | ((u32)f2bf(a.w) << 16);
      float4 b = *(const float4*)(W + (size_t)(n0 + row) * 1024 + k0 + c4);
      *(u32*)&Bs[row][c4]     = (u32)f2bf(b.x) | ((u32)f2bf(b.y) << 16);
      *(u32*)&Bs[row][c4 + 2] = (u32)f2bf(b.z) | ((u32)f2bf(b.w) << 16);
    }
    __syncthreads();
    s16x8 af[4], bf[4];
#pragma unroll
    for (int m = 0; m < 4; ++m)
      af[m] = *(const s16x8*)&As[wr + m * 16 + lr][lg * 8];
#pragma unroll
    for (int n = 0; n < 4; ++n)
      bf[n] = *(const s16x8*)&Bs[wc + n * 16 + lr][lg * 8];
#pragma unroll
    for (int m = 0; m < 4; ++m)
#pragma unroll
      for (int n = 0; n < 4; ++n)
        acc[m][n] = __builtin_amdgcn_mfma_f32_16x16x32_bf16(af[m], bf[n],
                                                            acc[m][n], 0, 0, 0);
    __syncthreads();
  }

  // Epilogue
  u16* dst01 = (which == 0) ? qh : kh;
#pragma unroll
  for (int m = 0; m < 4; ++m) {
#pragma unroll
    for (int n = 0; n < 4; ++n) {
#pragma unroll
      for (int i = 0; i < 4; ++i) {
        int row = m0 + wr + m * 16 + 4 * lg + i;  // token index b*S+s
        int col = n0 + wc + n * 16 + lr;          // d index h*64+hd
        float val = acc[m][n][i] + bias[col];
        int bbi = row >> 11, ss = row & 2047;
        int hhd = col >> 6, hd = col & 63;
        if (which < 2) {
          dst01[(((size_t)bbi * NH + hhd) * NS + ss) * 64 + hd] = f2bf(val);
        } else {
          vT[(((size_t)bbi * NH + hhd) * 64 + hd) * NS + ss] = f2bf(val);
        }
      }
    }
  }
}

// ---------------------------------------------------------------------------
// Causal flash attention. Grid: (32 qblocks, 16 heads, 2 batch), 4 waves.
// Each wave owns 16 q rows. KV tile = 64. Online softmax in D-layout.
// ---------------------------------------------------------------------------
__global__ __launch_bounds__(256) void attn_kernel(
    const u16* __restrict__ qh, const u16* __restrict__ kh,
    const u16* __restrict__ vT, u16* __restrict__ z) {
  const int qblk = blockIdx.x;
  const int hh = blockIdx.y;
  const int bb = blockIdx.z;
  const int tid = threadIdx.x;
  const int w = tid >> 6, l = tid & 63, lr = l & 15, lg = l >> 4;
  const int bh = bb * NH + hh;
  const int q0 = qblk * 64;

  __shared__ u16 Kt[64][72];      // [ki][hd]
  __shared__ u16 Vt[64][72];      // [hd][ki]  (from vT)
  __shared__ u16 Ps[4][16][72];   // per-wave P tile [qrow][ki]

  // Q fragments held in registers for the whole kernel
  s16x8 aq[2];
  {
    const u16* qp = qh + ((size_t)bh * NS + q0 + w * 16 + lr) * 64 + lg * 8;
    aq[0] = *(const s16x8*)qp;
    aq[1] = *(const s16x8*)(qp + 32);
  }

  const f32x4 fzero = {0.f, 0.f, 0.f, 0.f};
  float m_i[4] = {-1e30f, -1e30f, -1e30f, -1e30f};
  float l_i[4] = {0.f, 0.f, 0.f, 0.f};
  f32x4 acc_o[4];
#pragma unroll
  for (int n = 0; n < 4; ++n) acc_o[n] = fzero;

  for (int t = 0; t <= qblk; ++t) {
    const int s0 = t * 64;
#pragma unroll
    for (int i = 0; i < 2; ++i) {
      int idx = tid + i * 256;
      int row = idx >> 3, c8 = (idx & 7) * 8;
      *(s16x8*)&Kt[row][c8] =
          *(const s16x8*)(kh + ((size_t)bh * NS + s0 + row) * 64 + c8);
      *(s16x8*)&Vt[row][c8] =
          *(const s16x8*)(vT + ((size_t)bh * 64 + row) * NS + s0 + c8);
    }
    __syncthreads();

    // QK^T -> scores for this wave's 16 q rows x 64 ki
    f32x4 accs[4];
#pragma unroll
    for (int n = 0; n < 4; ++n) accs[n] = fzero;
#pragma unroll
    for (int n = 0; n < 4; ++n)
#pragma unroll
      for (int kk = 0; kk < 2; ++kk) {
        s16x8 bk = *(const s16x8*)&Kt[n * 16 + lr][kk * 32 + lg * 8];
        accs[n] = __builtin_amdgcn_mfma_f32_16x16x32_bf16(aq[kk], bk, accs[n],
                                                          0, 0, 0);
      }

    const bool diag = (t == qblk);
    float sv[4][4];
#pragma unroll
    for (int n = 0; n < 4; ++n)
#pragma unroll
      for (int i = 0; i < 4; ++i) {
        float x = accs[n][i] * 0.125f;  // 1/sqrt(64)
        if (diag && (n * 16 + lr > w * 16 + 4 * lg + i)) x = -1e30f;
        sv[n][i] = x;
      }

    // online softmax, per row i (row-group = 16 lanes sharing lg)
#pragma unroll
    for (int i = 0; i < 4; ++i) {
      float tm = fmaxf(fmaxf(sv[0][i], sv[1][i]), fmaxf(sv[2][i], sv[3][i]));
#pragma unroll
      for (int off = 1; off < 16; off <<= 1)
        tm = fmaxf(tm, __shfl_xor(tm, off, 64));
      float mnew = fmaxf(m_i[i], tm);
      float fscale = __expf(m_i[i] - mnew);
      m_i[i] = mnew;
      l_i[i] *= fscale;
#pragma unroll
      for (int n = 0; n < 4; ++n) acc_o[n][i] *= fscale;
      float psum = 0.f;
#pragma unroll
      for (int n = 0; n < 4; ++n) {
        float p = __expf(sv[n][i] - mnew);
        psum += p;
        Ps[w][4 * lg + i][n * 16 + lr] = f2bf(p);  // D-layout -> [q][ki]
      }
#pragma unroll
      for (int off = 1; off < 16; off <<= 1) psum += __shfl_xor(psum, off, 64);
      l_i[i] += psum;
    }

    // PV: acc_o += P @ V  (P from wave-local LDS, V^T rows contiguous)
#pragma unroll
    for (int kk = 0; kk < 2; ++kk) {
      s16x8 pa = *(const s16x8*)&Ps[w][lr][kk * 32 + lg * 8];
#pragma unroll
      for (int n = 0; n < 4; ++n) {
        s16x8 bv = *(const s16x8*)&Vt[n * 16 + lr][kk * 32 + lg * 8];
        acc_o[n] = __builtin_amdgcn_mfma_f32_16x16x32_bf16(pa, bv, acc_o[n],
                                                           0, 0, 0);
      }
    }
    __syncthreads();
  }

  // epilogue: normalize and write merged-head z [B,S,D] bf16
  const int qrow_base = q0 + w * 16 + 4 * lg;
#pragma unroll
  for (int i = 0; i < 4; ++i) {
    float inv = 1.f / l_i[i];
    size_t rbase = ((size_t)bb * NS + qrow_base + i) * ND + hh * 64;
#pragma unroll
    for (int n = 0; n < 4; ++n)
      z[rbase + n * 16 + lr] = f2bf(acc_o[n][i] * inv);
  }
}

// ---------------------------------------------------------------------------
// Output projection: z[4096,1024](bf16) @ Wo^T + bo -> fp32 out
// ---------------------------------------------------------------------------
__global__ __launch_bounds__(256) void proj_out_kernel(
    const u16* __restrict__ zin, const float* __restrict__ Wo,
    const float* __restrict__ bo, float* __restrict__ out) {
  const int m0 = blockIdx.y * 128, n0 = blockIdx.x * 128;
  const int tid = threadIdx.x;
  const int w = tid >> 6, l = tid & 63, lr = l & 15, lg = l >> 4;
  const int wr = (w >> 1) * 64, wc = (w & 1) * 64;

  __shared__ u16 As[128][40];
  __shared__ u16 Bs[128][40];

  const f32x4 fzero = {0.f, 0.f, 0.f, 0.f};
  f32x4 acc[4][4];
#pragma unroll
  for (int m = 0; m < 4; ++m)
#pragma unroll
    for (int n = 0; n < 4; ++n) acc[m][n] = fzero;

  for (int k0 = 0; k0 < 1024; k0 += 32) {
#pragma unroll
    for (int i = 0; i < 2; ++i) {
      int idx = tid + i * 256;
      int row = idx >> 2, c8 = (idx & 3) * 8;
      *(s16x8*)&As[row][c8] =
          *(const s16x8*)(zin + (size_t)(m0 + row) * 1024 + k0 + c8);
    }
#pragma unroll
    for (int i = 0; i < 4; ++i) {
      int idx = tid + i * 256;
      int row = idx >> 3, c4 = (idx & 7) * 4;
      float4 b = *(const float4*)(Wo + (size_t)(n0 + row) * 1024 + k0 + c4);
      *(u32*)&Bs[row][c4]     = (u32)f2bf(b.x) | ((u32)f2bf(b.y) << 16);
      *(u32*)&Bs[row][c4 + 2] = (u32)f2bf(b.z) | ((u32)f2bf(b.w) << 16);
    }
    __syncthreads();
    s16x8 af[4], bf[4];
#pragma unroll
    for (int m = 0; m < 4; ++m)
      af[m] = *(const s16x8*)&As[wr + m * 16 + lr][lg * 8];
#pragma unroll
    for (int n = 0; n < 4; ++n)
      bf[n] = *(const s16x8*)&Bs[wc + n * 16 + lr][lg * 8];
#pragma unroll
    for (int m = 0; m < 4; ++m)
#pragma unroll
      for (int n = 0; n < 4; ++n)
        acc[m][n] = __builtin_amdgcn_mfma_f32_16x16x32_bf16(af[m], bf[n],
                                                            acc[m][n], 0, 0, 0);
    __syncthreads();
  }

#pragma unroll
  for (int m = 0; m < 4; ++m)
#pragma unroll
    for (int n = 0; n < 4; ++n)
#pragma unroll
      for (int i = 0; i < 4; ++i) {
        int row = m0 + wr + m * 16 + 4 * lg + i;
        int col = n0 + wc + n * 16 + lr;
        out[(size_t)row * 1024 + col] = acc[m][n][i] + bo[col];
      }
}

// ---------------------------------------------------------------------------
extern "C" void kernel_launch(void* const* d_in, const int* in_sizes, int n_in,
                              void* d_out, int out_size, void* d_ws,
                              size_t ws_size, hipStream_t stream) {
  const float* Q = (const float*)d_in[0];
  const float* K = (const float*)d_in[1];
  const float* V = (const float*)d_in[2];
  // d_in[3] = causal mask (tril) -- semantics hardcoded in attn kernel
  const float* Wq = (const float*)d_in[4];
  const float* bq = (const float*)d_in[5];
  const float* Wk = (const float*)d_in[6];
  const float* bk = (const float*)d_in[7];
  const float* Wv = (const float*)d_in[8];
  const float* bv = (const float*)d_in[9];
  const float* Wo = (const float*)d_in[10];
  const float* bo = (const float*)d_in[11];
  float* out = (float*)d_out;

  const size_t NTOK = (size_t)NB * NS * ND;  // 4M elements
  u16* qh = (u16*)d_ws;        // [B,H,S,64]
  u16* kh = qh + NTOK;         // [B,H,S,64]
  u16* vT = kh + NTOK;         // [B,H,64,S]
  u16* zz = vT + NTOK;         // [B,S,D]

  proj_qkv_kernel<<<dim3(8, 32, 3), 256, 0, stream>>>(Q, K, V, Wq, bq, Wk, bk,
                                                      Wv, bv, qh, kh, vT);
  attn_kernel<<<dim3(32, 16, 2), 256, 0, stream>>>(qh, kh, vT, zz);
  proj_out_kernel<<<dim3(8, 32), 256, 0, stream>>>(zz, Wo, bo, out);
}

// Round 2
// 194.210 us; speedup vs baseline: 1.2588x; 1.2588x over previous
//
#include <hip/hip_runtime.h>
#include <hip/hip_bf16.h>

typedef unsigned short u16;
typedef unsigned int u32;
typedef __attribute__((ext_vector_type(8))) short s16x8;
typedef __attribute__((ext_vector_type(4))) float f32x4;
typedef __attribute__((ext_vector_type(16))) float f32x16;

#define NB 2
#define NH 16
#define NS 2048
#define ND 1024
#define QSCALE 0.1803368801111244f  // 0.125 * log2(e)  (exp2-domain softmax)

__device__ __forceinline__ u16 f2bf(float f) {
  u32 u = __float_as_uint(f);
  u = u + 0x7FFFu + ((u >> 16) & 1u);
  return (u16)(u >> 16);
}

__device__ __forceinline__ u32 pkbf(float a, float b) {
  __hip_bfloat162 h = __float22bfloat162_rn(make_float2(a, b));
  union { __hip_bfloat162 h; u32 u; } cv;
  cv.h = h;
  return cv.u;
}

// ---------------------------------------------------------------------------
// QKV projection: X[4096,1024] @ W^T + b.
// which=0 (q): head-split bf16 [B,H,S,64], PRE-SCALED by QSCALE
// which=1 (k): head-split bf16 [B,H,S,64]
// which=2 (v): transposed bf16 [B,H,64,S]
// ---------------------------------------------------------------------------
__global__ __launch_bounds__(256) void proj_qkv_kernel(
    const float* __restrict__ Qin, const float* __restrict__ Kin,
    const float* __restrict__ Vin,
    const float* __restrict__ Wq, const float* __restrict__ bq,
    const float* __restrict__ Wk, const float* __restrict__ bk,
    const float* __restrict__ Wv, const float* __restrict__ bv,
    u16* __restrict__ qh, u16* __restrict__ kh, u16* __restrict__ vT) {
  const int which = blockIdx.z;
  const float* X = (which == 0) ? Qin : (which == 1) ? Kin : Vin;
  const float* W = (which == 0) ? Wq : (which == 1) ? Wk : Wv;
  const float* bias = (which == 0) ? bq : (which == 1) ? bk : bv;

  const int m0 = blockIdx.y * 128, n0 = blockIdx.x * 128;
  const int tid = threadIdx.x;
  const int w = tid >> 6, l = tid & 63, lr = l & 15, lg = l >> 4;
  const int wr = (w >> 1) * 64, wc = (w & 1) * 64;

  __shared__ u16 As[128][40];
  __shared__ u16 Bs[128][40];

  const f32x4 fzero = {0.f, 0.f, 0.f, 0.f};
  f32x4 acc[4][4];
#pragma unroll
  for (int m = 0; m < 4; ++m)
#pragma unroll
    for (int n = 0; n < 4; ++n) acc[m][n] = fzero;

  for (int k0 = 0; k0 < 1024; k0 += 32) {
#pragma unroll
    for (int i = 0; i < 4; ++i) {
      int idx = tid + i * 256;
      int row = idx >> 3, c4 = (idx & 7) * 4;
      float4 a = *(const float4*)(X + (size_t)(m0 + row) * 1024 + k0 + c4);
      *(u32*)&As[row][c4]     = (u32)f2bf(a.x) | ((u32)f2bf(a.y) << 16);
      *(u32*)&As[row][c4 + 2] = (u32)f2bf(a.z) | ((u32)f2bf(a.w) << 16);
      float4 b = *(const float4*)(W + (size_t)(n0 + row) * 1024 + k0 + c4);
      *(u32*)&Bs[row][c4]     = (u32)f2bf(b.x) | ((u32)f2bf(b.y) << 16);
      *(u32*)&Bs[row][c4 + 2] = (u32)f2bf(b.z) | ((u32)f2bf(b.w) << 16);
    }
    __syncthreads();
    s16x8 af[4], bf[4];
#pragma unroll
    for (int m = 0; m < 4; ++m)
      af[m] = *(const s16x8*)&As[wr + m * 16 + lr][lg * 8];
#pragma unroll
    for (int n = 0; n < 4; ++n)
      bf[n] = *(const s16x8*)&Bs[wc + n * 16 + lr][lg * 8];
#pragma unroll
    for (int m = 0; m < 4; ++m)
#pragma unroll
      for (int n = 0; n < 4; ++n)
        acc[m][n] = __builtin_amdgcn_mfma_f32_16x16x32_bf16(af[m], bf[n],
                                                            acc[m][n], 0, 0, 0);
    __syncthreads();
  }

  u16* dst01 = (which == 0) ? qh : kh;
#pragma unroll
  for (int m = 0; m < 4; ++m) {
#pragma unroll
    for (int n = 0; n < 4; ++n) {
#pragma unroll
      for (int i = 0; i < 4; ++i) {
        int row = m0 + wr + m * 16 + 4 * lg + i;  // token b*S+s
        int col = n0 + wc + n * 16 + lr;          // d = h*64+hd
        float val = acc[m][n][i] + bias[col];
        if (which == 0) val *= QSCALE;
        int bbi = row >> 11, ss = row & 2047;
        int hhd = col >> 6, hd = col & 63;
        if (which < 2) {
          dst01[(((size_t)bbi * NH + hhd) * NS + ss) * 64 + hd] = f2bf(val);
        } else {
          vT[(((size_t)bbi * NH + hhd) * 64 + hd) * NS + ss] = f2bf(val);
        }
      }
    }
  }
}

// ---------------------------------------------------------------------------
// Causal flash attention, swapped-operand 32x32x16 structure.
// 4 waves x 32 q-rows = 128 q/block. Grid (16 qblk desc, 16 heads, 2 batch).
// S^T = K·Q^T  (lane owns q = lane&31 -> lane-local softmax state)
// O^T = V^T·P^T (rescale lane-local); P kept in registers via shfl_xor(32).
// ---------------------------------------------------------------------------
__global__ __launch_bounds__(256) void attn_kernel(
    const u16* __restrict__ qh, const u16* __restrict__ kh,
    const u16* __restrict__ vT, u16* __restrict__ z) {
  const int qb = 15 - blockIdx.x;  // longest blocks dispatched first
  const int hh = blockIdx.y, bb = blockIdx.z;
  const int bh = bb * NH + hh;
  const int tid = threadIdx.x;
  const int w = tid >> 6, l = tid & 63;
  const int ql = l & 31;       // q column owned by this lane
  const int hi = l >> 5;       // lane half
  const int hi8 = hi * 8;
  const int q0b = qb * 128;
  const int q0w = q0b + w * 32;

  __shared__ u16 smem[2][64][72];  // K tile [kv][k], V^T tile [d][kv]; 144B rows

  // Q fragments (already scaled by QSCALE): Q[ql][k = st*16 + hi8 + j]
  s16x8 qf[4];
  {
    const u16* qp = qh + ((size_t)bh * NS + q0w + ql) * 64 + hi8;
#pragma unroll
    for (int st = 0; st < 4; ++st) qf[st] = *(const s16x8*)(qp + st * 16);
  }

  f32x16 o0 = {0, 0, 0, 0, 0, 0, 0, 0, 0, 0, 0, 0, 0, 0, 0, 0};
  f32x16 o1 = {0, 0, 0, 0, 0, 0, 0, 0, 0, 0, 0, 0, 0, 0, 0, 0};
  float m_run = -1e30f, l_run = 0.f;

  const int ntiles = (q0b + 128) >> 6;
  for (int t = 0; t < ntiles; ++t) {
    __syncthreads();
#pragma unroll
    for (int i = 0; i < 2; ++i) {
      int cid = tid + i * 256;
      int row = cid >> 3, c8 = (cid & 7) * 8;
      *(s16x8*)&smem[0][row][c8] =
          *(const s16x8*)(kh + ((size_t)bh * NS + t * 64 + row) * 64 + c8);
      *(s16x8*)&smem[1][row][c8] =
          *(const s16x8*)(vT + ((size_t)bh * 64 + row) * NS + t * 64 + c8);
    }
    __syncthreads();

#pragma unroll
    for (int sub = 0; sub < 2; ++sub) {
      const int kvg = t * 64 + sub * 32;
      if (kvg > q0w) continue;           // wave-uniform causal skip
      const bool masked = (kvg == q0w);  // diagonal subtile

      // S^T[kv][q]: 4 MFMAs over k=64
      f32x16 s = {0, 0, 0, 0, 0, 0, 0, 0, 0, 0, 0, 0, 0, 0, 0, 0};
#pragma unroll
      for (int st = 0; st < 4; ++st) {
        s16x8 ak = *(const s16x8*)&smem[0][sub * 32 + ql][st * 16 + hi8];
        s = __builtin_amdgcn_mfma_f32_32x32x16_bf16(ak, qf[st], s, 0, 0, 0);
      }

      float sv[16];
#pragma unroll
      for (int r = 0; r < 16; ++r) {
        float x = s[r];
        if (masked) {
          int kvloc = (r & 3) + 8 * (r >> 2) + 4 * hi;
          if (kvloc > ql) x = -1e30f;
        }
        sv[r] = x;
      }

      // row max (lane-local + partner half)
      float mx = sv[0];
#pragma unroll
      for (int r = 1; r < 16; ++r) mx = fmaxf(mx, sv[r]);
      mx = fmaxf(mx, __shfl_xor(mx, 32, 64));

      if (__any(mx > m_run)) {  // T13 deferred rescale
        float mnew = fmaxf(m_run, mx);
        float fs = __builtin_amdgcn_exp2f(m_run - mnew);
#pragma unroll
        for (int r = 0; r < 16; ++r) {
          o0[r] *= fs;
          o1[r] *= fs;
        }
        l_run *= fs;
        m_run = mnew;
      }

      // P = exp2(S - m), pack to bf16 pairs; row sum
      float ps = 0.f;
      u32 pk[8];
#pragma unroll
      for (int tt = 0; tt < 8; ++tt) {
        float a = __builtin_amdgcn_exp2f(sv[2 * tt] - m_run);
        float b = __builtin_amdgcn_exp2f(sv[2 * tt + 1] - m_run);
        ps += a + b;
        pk[tt] = pkbf(a, b);
      }
      ps += __shfl_xor(ps, 32, 64);
      l_run += ps;

      // exchange halves: partner's packed P values
      u32 qk[8];
#pragma unroll
      for (int tt = 0; tt < 8; ++tt) qk[tt] = __shfl_xor(pk[tt], 32, 64);

      // PV B-fragments: P^T[kv = k0 + hi8 + j][q=ql]
      union { u32 u[4]; s16x8 h; } pf0, pf1;
      pf0.u[0] = hi ? qk[2] : pk[0];
      pf0.u[1] = hi ? qk[3] : pk[1];
      pf0.u[2] = hi ? pk[2] : qk[0];
      pf0.u[3] = hi ? pk[3] : qk[1];
      pf1.u[0] = hi ? qk[6] : pk[4];
      pf1.u[1] = hi ? qk[7] : pk[5];
      pf1.u[2] = hi ? pk[6] : qk[4];
      pf1.u[3] = hi ? pk[7] : qk[5];

      // O^T += V^T · P^T : 2 d-tiles x 2 kv-steps
#pragma unroll
      for (int k2 = 0; k2 < 2; ++k2) {
        s16x8 pa = (k2 == 0) ? pf0.h : pf1.h;
        s16x8 av0 = *(const s16x8*)&smem[1][ql][sub * 32 + k2 * 16 + hi8];
        s16x8 av1 = *(const s16x8*)&smem[1][32 + ql][sub * 32 + k2 * 16 + hi8];
        o0 = __builtin_amdgcn_mfma_f32_32x32x16_bf16(av0, pa, o0, 0, 0, 0);
        o1 = __builtin_amdgcn_mfma_f32_32x32x16_bf16(av1, pa, o1, 0, 0, 0);
      }
    }
  }

  __syncthreads();  // all compute done; reuse smem per-wave for transpose
  float inv = 1.f / l_run;
  u16* Zw = &smem[0][0][0] + w * (32 * 72);  // per-wave [32 q][72] region
#pragma unroll
  for (int r = 0; r < 16; r += 2) {
    int d0 = (r & 3) + 8 * (r >> 2) + 4 * hi;
    *(u32*)&Zw[ql * 72 + d0]      = pkbf(o0[r] * inv, o0[r + 1] * inv);
    *(u32*)&Zw[ql * 72 + 32 + d0] = pkbf(o1[r] * inv, o1[r + 1] * inv);
  }
  // same-wave LDS readback (compiler inserts lgkmcnt), coalesced global store
#pragma unroll
  for (int i = 0; i < 4; ++i) {
    int cid = i * 64 + l;
    int row = cid >> 3, c8 = (cid & 7) * 8;
    s16x8 vv = *(const s16x8*)&Zw[row * 72 + c8];
    *(s16x8*)(z + ((size_t)bb * NS + q0w + row) * ND + hh * 64 + c8) = vv;
  }
}

// ---------------------------------------------------------------------------
// Output projection: z[4096,1024](bf16) @ Wo^T + bo -> fp32 out
// ---------------------------------------------------------------------------
__global__ __launch_bounds__(256) void proj_out_kernel(
    const u16* __restrict__ zin, const float* __restrict__ Wo,
    const float* __restrict__ bo, float* __restrict__ out) {
  const int m0 = blockIdx.y * 128, n0 = blockIdx.x * 128;
  const int tid = threadIdx.x;
  const int w = tid >> 6, l = tid & 63, lr = l & 15, lg = l >> 4;
  const int wr = (w >> 1) * 64, wc = (w & 1) * 64;

  __shared__ u16 As[128][40];
  __shared__ u16 Bs[128][40];

  const f32x4 fzero = {0.f, 0.f, 0.f, 0.f};
  f32x4 acc[4][4];
#pragma unroll
  for (int m = 0; m < 4; ++m)
#pragma unroll
    for (int n = 0; n < 4; ++n) acc[m][n] = fzero;

  for (int k0 = 0; k0 < 1024; k0 += 32) {
#pragma unroll
    for (int i = 0; i < 2; ++i) {
      int idx = tid + i * 256;
      int row = idx >> 2, c8 = (idx & 3) * 8;
      *(s16x8*)&As[row][c8] =
          *(const s16x8*)(zin + (size_t)(m0 + row) * 1024 + k0 + c8);
    }
#pragma unroll
    for (int i = 0; i < 4; ++i) {
      int idx = tid + i * 256;
      int row = idx >> 3, c4 = (idx & 7) * 4;
      float4 b = *(const float4*)(Wo + (size_t)(n0 + row) * 1024 + k0 + c4);
      *(u32*)&Bs[row][c4]     = (u32)f2bf(b.x) | ((u32)f2bf(b.y) << 16);
      *(u32*)&Bs[row][c4 + 2] = (u32)f2bf(b.z) | ((u32)f2bf(b.w) << 16);
    }
    __syncthreads();
    s16x8 af[4], bf[4];
#pragma unroll
    for (int m = 0; m < 4; ++m)
      af[m] = *(const s16x8*)&As[wr + m * 16 + lr][lg * 8];
#pragma unroll
    for (int n = 0; n < 4; ++n)
      bf[n] = *(const s16x8*)&Bs[wc + n * 16 + lr][lg * 8];
#pragma unroll
    for (int m = 0; m < 4; ++m)
#pragma unroll
      for (int n = 0; n < 4; ++n)
        acc[m][n] = __builtin_amdgcn_mfma_f32_16x16x32_bf16(af[m], bf[n],
                                                            acc[m][n], 0, 0, 0);
    __syncthreads();
  }

#pragma unroll
  for (int m = 0; m < 4; ++m)
#pragma unroll
    for (int n = 0; n < 4; ++n)
#pragma unroll
      for (int i = 0; i < 4; ++i) {
        int row = m0 + wr + m * 16 + 4 * lg + i;
        int col = n0 + wc + n * 16 + lr;
        out[(size_t)row * 1024 + col] = acc[m][n][i] + bo[col];
      }
}

// ---------------------------------------------------------------------------
extern "C" void kernel_launch(void* const* d_in, const int* in_sizes, int n_in,
                              void* d_out, int out_size, void* d_ws,
                              size_t ws_size, hipStream_t stream) {
  const float* Q = (const float*)d_in[0];
  const float* K = (const float*)d_in[1];
  const float* V = (const float*)d_in[2];
  // d_in[3] = causal mask (tril) -- semantics hardcoded in attn kernel
  const float* Wq = (const float*)d_in[4];
  const float* bq = (const float*)d_in[5];
  const float* Wk = (const float*)d_in[6];
  const float* bk = (const float*)d_in[7];
  const float* Wv = (const float*)d_in[8];
  const float* bv = (const float*)d_in[9];
  const float* Wo = (const float*)d_in[10];
  const float* bo = (const float*)d_in[11];
  float* out = (float*)d_out;

  const size_t NTOK = (size_t)NB * NS * ND;  // 4M elements
  u16* qh = (u16*)d_ws;        // [B,H,S,64] (prescaled)
  u16* kh = qh + NTOK;         // [B,H,S,64]
  u16* vT = kh + NTOK;         // [B,H,64,S]
  u16* zz = vT + NTOK;         // [B,S,D]

  proj_qkv_kernel<<<dim3(8, 32, 3), 256, 0, stream>>>(Q, K, V, Wq, bq, Wk, bk,
                                                      Wv, bv, qh, kh, vT);
  attn_kernel<<<dim3(16, NH, NB), 256, 0, stream>>>(qh, kh, vT, zz);
  proj_out_kernel<<<dim3(8, 32), 256, 0, stream>>>(zz, Wo, bo, out);
}

// Round 3
// 148.904 us; speedup vs baseline: 1.6418x; 1.3043x over previous
//
#include <hip/hip_runtime.h>
#include <hip/hip_bf16.h>

typedef unsigned short u16;
typedef unsigned int u32;
typedef __attribute__((ext_vector_type(8))) short s16x8;
typedef __attribute__((ext_vector_type(4))) float f32x4;
typedef __attribute__((ext_vector_type(16))) float f32x16;

#define NB 2
#define NH 16
#define NS 2048
#define ND 1024
#define QSCALE 0.1803368801111244f  // 0.125 * log2(e)

#define AS1(p) ((const __attribute__((address_space(1))) void*)(p))
#define AS3(p) ((__attribute__((address_space(3))) void*)(p))

__device__ __forceinline__ u16 f2bf(float f) {
  u32 u = __float_as_uint(f);
  u = u + 0x7FFFu + ((u >> 16) & 1u);
  return (u16)(u >> 16);
}

__device__ __forceinline__ u32 pkbf(float a, float b) {
  __hip_bfloat162 h = __float22bfloat162_rn(make_float2(a, b));
  union { __hip_bfloat162 h; u32 u; } cv;
  cv.h = h;
  return cv.u;
}

// ---------------------------------------------------------------------------
// fp32 -> bf16 conversion: z=0..2 -> Q,K,V (4M each); z=3..6 -> Wq,Wk,Wv,Wo
// ---------------------------------------------------------------------------
__global__ __launch_bounds__(256) void cvt_kernel(
    const float* __restrict__ q, const float* __restrict__ k,
    const float* __restrict__ v, const float* __restrict__ wq,
    const float* __restrict__ wk, const float* __restrict__ wv,
    const float* __restrict__ wo, u16* __restrict__ Xbf,
    u16* __restrict__ Wbf) {
  const int z = blockIdx.z;
  const float* src;
  u16* dst;
  size_t n;
  const size_t NX = (size_t)4096 * 1024, NW = (size_t)1024 * 1024;
  if (z == 0)      { src = q;  dst = Xbf;          n = NX; }
  else if (z == 1) { src = k;  dst = Xbf + NX;     n = NX; }
  else if (z == 2) { src = v;  dst = Xbf + 2 * NX; n = NX; }
  else if (z == 3) { src = wq; dst = Wbf;          n = NW; }
  else if (z == 4) { src = wk; dst = Wbf + NW;     n = NW; }
  else if (z == 5) { src = wv; dst = Wbf + 2 * NW; n = NW; }
  else             { src = wo; dst = Wbf + 3 * NW; n = NW; }
  const size_t n4 = n >> 2;
  for (size_t i = (size_t)blockIdx.x * 256 + threadIdx.x; i < n4;
       i += (size_t)gridDim.x * 256) {
    float4 a = ((const float4*)src)[i];
    uint2 p;
    p.x = (u32)f2bf(a.x) | ((u32)f2bf(a.y) << 16);
    p.y = (u32)f2bf(a.z) | ((u32)f2bf(a.w) << 16);
    ((uint2*)dst)[i] = p;
  }
}

// ---------------------------------------------------------------------------
// Fast m97-style 128x128 GEMM (bf16 in, BK=32, global_load_lds width 16).
// LDS linear [128][32] bf16; source-column XOR swizzle (k4 ^= row&3) +
// matching swizzled ds_read -> <=4-way bank conflict.
// ---------------------------------------------------------------------------
__global__ __launch_bounds__(256) void gemm_qkv_fast(
    const u16* __restrict__ Xbf, const u16* __restrict__ Wbf,
    const float* __restrict__ bq, const float* __restrict__ bk,
    const float* __restrict__ bv, u16* __restrict__ qh, u16* __restrict__ kh,
    u16* __restrict__ vT) {
  const int which = blockIdx.z;
  const u16* A = Xbf + (size_t)which * 4096 * 1024;
  const u16* B = Wbf + (size_t)which * 1024 * 1024;
  const float* bias = (which == 0) ? bq : (which == 1) ? bk : bv;
  const int m0 = blockIdx.y * 128, n0 = blockIdx.x * 128;
  const int tid = threadIdx.x;
  const int w = tid >> 6, l = tid & 63, lr = l & 15, lg = l >> 4;
  const int wr = (w >> 1) * 64, wc = (w & 1) * 64;

  __shared__ u16 As[128 * 32];
  __shared__ u16 Bs[128 * 32];

  const f32x4 fzero = {0.f, 0.f, 0.f, 0.f};
  f32x4 acc[4][4];
#pragma unroll
  for (int m = 0; m < 4; ++m)
#pragma unroll
    for (int n = 0; n < 4; ++n) acc[m][n] = fzero;

  for (int k0 = 0; k0 < 1024; k0 += 32) {
#pragma unroll
    for (int i = 0; i < 2; ++i) {
      int c = i * 256 + tid;
      int row = c >> 2, k4 = (c & 3) ^ (row & 3);
      const u16* sa = A + (size_t)(m0 + row) * 1024 + k0 + k4 * 8;
      const u16* sb = B + (size_t)(n0 + row) * 1024 + k0 + k4 * 8;
      u16* da = As + (i * 256 + w * 64) * 8;  // wave-uniform dest base
      u16* db = Bs + (i * 256 + w * 64) * 8;
      __builtin_amdgcn_global_load_lds(AS1(sa), AS3(da), 16, 0, 0);
      __builtin_amdgcn_global_load_lds(AS1(sb), AS3(db), 16, 0, 0);
    }
    __syncthreads();
    s16x8 af[4], bf[4];
#pragma unroll
    for (int m = 0; m < 4; ++m) {
      int row = wr + m * 16 + lr;
      af[m] = *(const s16x8*)(As + row * 32 + ((lg ^ (row & 3)) * 8));
    }
#pragma unroll
    for (int n = 0; n < 4; ++n) {
      int row = wc + n * 16 + lr;
      bf[n] = *(const s16x8*)(Bs + row * 32 + ((lg ^ (row & 3)) * 8));
    }
#pragma unroll
    for (int m = 0; m < 4; ++m)
#pragma unroll
      for (int n = 0; n < 4; ++n)
        acc[m][n] = __builtin_amdgcn_mfma_f32_16x16x32_bf16(af[m], bf[n],
                                                            acc[m][n], 0, 0, 0);
    __syncthreads();
  }

#pragma unroll
  for (int m = 0; m < 4; ++m) {
#pragma unroll
    for (int n = 0; n < 4; ++n) {
#pragma unroll
      for (int i = 0; i < 4; ++i) {
        int row = m0 + wr + m * 16 + 4 * lg + i;
        int col = n0 + wc + n * 16 + lr;
        float val = acc[m][n][i] + bias[col];
        if (which == 0) val *= QSCALE;
        int bbi = row >> 11, ss = row & 2047;
        int hhd = col >> 6, hd = col & 63;
        if (which == 0) {
          qh[(((size_t)bbi * NH + hhd) * NS + ss) * 64 + hd] = f2bf(val);
        } else if (which == 1) {
          kh[(((size_t)bbi * NH + hhd) * NS + ss) * 64 + hd] = f2bf(val);
        } else {
          vT[(((size_t)bbi * NH + hhd) * 64 + hd) * NS + ss] = f2bf(val);
        }
      }
    }
  }
}

__global__ __launch_bounds__(256) void gemm_out_fast(
    const u16* __restrict__ zin, const u16* __restrict__ Wbf,
    const float* __restrict__ bo, float* __restrict__ out) {
  const u16* B = Wbf + (size_t)3 * 1024 * 1024;
  const int m0 = blockIdx.y * 128, n0 = blockIdx.x * 128;
  const int tid = threadIdx.x;
  const int w = tid >> 6, l = tid & 63, lr = l & 15, lg = l >> 4;
  const int wr = (w >> 1) * 64, wc = (w & 1) * 64;

  __shared__ u16 As[128 * 32];
  __shared__ u16 Bs[128 * 32];

  const f32x4 fzero = {0.f, 0.f, 0.f, 0.f};
  f32x4 acc[4][4];
#pragma unroll
  for (int m = 0; m < 4; ++m)
#pragma unroll
    for (int n = 0; n < 4; ++n) acc[m][n] = fzero;

  for (int k0 = 0; k0 < 1024; k0 += 32) {
#pragma unroll
    for (int i = 0; i < 2; ++i) {
      int c = i * 256 + tid;
      int row = c >> 2, k4 = (c & 3) ^ (row & 3);
      const u16* sa = zin + (size_t)(m0 + row) * 1024 + k0 + k4 * 8;
      const u16* sb = B + (size_t)(n0 + row) * 1024 + k0 + k4 * 8;
      u16* da = As + (i * 256 + w * 64) * 8;
      u16* db = Bs + (i * 256 + w * 64) * 8;
      __builtin_amdgcn_global_load_lds(AS1(sa), AS3(da), 16, 0, 0);
      __builtin_amdgcn_global_load_lds(AS1(sb), AS3(db), 16, 0, 0);
    }
    __syncthreads();
    s16x8 af[4], bf[4];
#pragma unroll
    for (int m = 0; m < 4; ++m) {
      int row = wr + m * 16 + lr;
      af[m] = *(const s16x8*)(As + row * 32 + ((lg ^ (row & 3)) * 8));
    }
#pragma unroll
    for (int n = 0; n < 4; ++n) {
      int row = wc + n * 16 + lr;
      bf[n] = *(const s16x8*)(Bs + row * 32 + ((lg ^ (row & 3)) * 8));
    }
#pragma unroll
    for (int m = 0; m < 4; ++m)
#pragma unroll
      for (int n = 0; n < 4; ++n)
        acc[m][n] = __builtin_amdgcn_mfma_f32_16x16x32_bf16(af[m], bf[n],
                                                            acc[m][n], 0, 0, 0);
    __syncthreads();
  }

#pragma unroll
  for (int m = 0; m < 4; ++m)
#pragma unroll
    for (int n = 0; n < 4; ++n)
#pragma unroll
      for (int i = 0; i < 4; ++i) {
        int row = m0 + wr + m * 16 + 4 * lg + i;
        int col = n0 + wc + n * 16 + lr;
        out[(size_t)row * 1024 + col] = acc[m][n][i] + bo[col];
      }
}

// ---------------------------------------------------------------------------
// Fallback (fp32-input) projection kernels, verified in round 2.
// ---------------------------------------------------------------------------
__global__ __launch_bounds__(256) void proj_qkv_kernel(
    const float* __restrict__ Qin, const float* __restrict__ Kin,
    const float* __restrict__ Vin,
    const float* __restrict__ Wq, const float* __restrict__ bq,
    const float* __restrict__ Wk, const float* __restrict__ bk,
    const float* __restrict__ Wv, const float* __restrict__ bv,
    u16* __restrict__ qh, u16* __restrict__ kh, u16* __restrict__ vT) {
  const int which = blockIdx.z;
  const float* X = (which == 0) ? Qin : (which == 1) ? Kin : Vin;
  const float* W = (which == 0) ? Wq : (which == 1) ? Wk : Wv;
  const float* bias = (which == 0) ? bq : (which == 1) ? bk : bv;

  const int m0 = blockIdx.y * 128, n0 = blockIdx.x * 128;
  const int tid = threadIdx.x;
  const int w = tid >> 6, l = tid & 63, lr = l & 15, lg = l >> 4;
  const int wr = (w >> 1) * 64, wc = (w & 1) * 64;

  __shared__ u16 As[128][40];
  __shared__ u16 Bs[128][40];

  const f32x4 fzero = {0.f, 0.f, 0.f, 0.f};
  f32x4 acc[4][4];
#pragma unroll
  for (int m = 0; m < 4; ++m)
#pragma unroll
    for (int n = 0; n < 4; ++n) acc[m][n] = fzero;

  for (int k0 = 0; k0 < 1024; k0 += 32) {
#pragma unroll
    for (int i = 0; i < 4; ++i) {
      int idx = tid + i * 256;
      int row = idx >> 3, c4 = (idx & 7) * 4;
      float4 a = *(const float4*)(X + (size_t)(m0 + row) * 1024 + k0 + c4);
      *(u32*)&As[row][c4]     = (u32)f2bf(a.x) | ((u32)f2bf(a.y) << 16);
      *(u32*)&As[row][c4 + 2] = (u32)f2bf(a.z) | ((u32)f2bf(a.w) << 16);
      float4 b = *(const float4*)(W + (size_t)(n0 + row) * 1024 + k0 + c4);
      *(u32*)&Bs[row][c4]     = (u32)f2bf(b.x) | ((u32)f2bf(b.y) << 16);
      *(u32*)&Bs[row][c4 + 2] = (u32)f2bf(b.z) | ((u32)f2bf(b.w) << 16);
    }
    __syncthreads();
    s16x8 af[4], bf[4];
#pragma unroll
    for (int m = 0; m < 4; ++m)
      af[m] = *(const s16x8*)&As[wr + m * 16 + lr][lg * 8];
#pragma unroll
    for (int n = 0; n < 4; ++n)
      bf[n] = *(const s16x8*)&Bs[wc + n * 16 + lr][lg * 8];
#pragma unroll
    for (int m = 0; m < 4; ++m)
#pragma unroll
      for (int n = 0; n < 4; ++n)
        acc[m][n] = __builtin_amdgcn_mfma_f32_16x16x32_bf16(af[m], bf[n],
                                                            acc[m][n], 0, 0, 0);
    __syncthreads();
  }

  u16* dst01 = (which == 0) ? qh : kh;
#pragma unroll
  for (int m = 0; m < 4; ++m) {
#pragma unroll
    for (int n = 0; n < 4; ++n) {
#pragma unroll
      for (int i = 0; i < 4; ++i) {
        int row = m0 + wr + m * 16 + 4 * lg + i;
        int col = n0 + wc + n * 16 + lr;
        float val = acc[m][n][i] + bias[col];
        if (which == 0) val *= QSCALE;
        int bbi = row >> 11, ss = row & 2047;
        int hhd = col >> 6, hd = col & 63;
        if (which < 2) {
          dst01[(((size_t)bbi * NH + hhd) * NS + ss) * 64 + hd] = f2bf(val);
        } else {
          vT[(((size_t)bbi * NH + hhd) * 64 + hd) * NS + ss] = f2bf(val);
        }
      }
    }
  }
}

__global__ __launch_bounds__(256) void proj_out_kernel(
    const u16* __restrict__ zin, const float* __restrict__ Wo,
    const float* __restrict__ bo, float* __restrict__ out) {
  const int m0 = blockIdx.y * 128, n0 = blockIdx.x * 128;
  const int tid = threadIdx.x;
  const int w = tid >> 6, l = tid & 63, lr = l & 15, lg = l >> 4;
  const int wr = (w >> 1) * 64, wc = (w & 1) * 64;

  __shared__ u16 As[128][40];
  __shared__ u16 Bs[128][40];

  const f32x4 fzero = {0.f, 0.f, 0.f, 0.f};
  f32x4 acc[4][4];
#pragma unroll
  for (int m = 0; m < 4; ++m)
#pragma unroll
    for (int n = 0; n < 4; ++n) acc[m][n] = fzero;

  for (int k0 = 0; k0 < 1024; k0 += 32) {
#pragma unroll
    for (int i = 0; i < 2; ++i) {
      int idx = tid + i * 256;
      int row = idx >> 2, c8 = (idx & 3) * 8;
      *(s16x8*)&As[row][c8] =
          *(const s16x8*)(zin + (size_t)(m0 + row) * 1024 + k0 + c8);
    }
#pragma unroll
    for (int i = 0; i < 4; ++i) {
      int idx = tid + i * 256;
      int row = idx >> 3, c4 = (idx & 7) * 4;
      float4 b = *(const float4*)(Wo + (size_t)(n0 + row) * 1024 + k0 + c4);
      *(u32*)&Bs[row][c4]     = (u32)f2bf(b.x) | ((u32)f2bf(b.y) << 16);
      *(u32*)&Bs[row][c4 + 2] = (u32)f2bf(b.z) | ((u32)f2bf(b.w) << 16);
    }
    __syncthreads();
    s16x8 af[4], bf[4];
#pragma unroll
    for (int m = 0; m < 4; ++m)
      af[m] = *(const s16x8*)&As[wr + m * 16 + lr][lg * 8];
#pragma unroll
    for (int n = 0; n < 4; ++n)
      bf[n] = *(const s16x8*)&Bs[wc + n * 16 + lr][lg * 8];
#pragma unroll
    for (int m = 0; m < 4; ++m)
#pragma unroll
      for (int n = 0; n < 4; ++n)
        acc[m][n] = __builtin_amdgcn_mfma_f32_16x16x32_bf16(af[m], bf[n],
                                                            acc[m][n], 0, 0, 0);
    __syncthreads();
  }

#pragma unroll
  for (int m = 0; m < 4; ++m)
#pragma unroll
    for (int n = 0; n < 4; ++n)
#pragma unroll
      for (int i = 0; i < 4; ++i) {
        int row = m0 + wr + m * 16 + 4 * lg + i;
        int col = n0 + wc + n * 16 + lr;
        out[(size_t)row * 1024 + col] = acc[m][n][i] + bo[col];
      }
}

// ---------------------------------------------------------------------------
// Causal flash attention (swapped 32x32x16), double-buffered global_load_lds
// staging (1 barrier/tile), XOR-swizzled LDS (k8 ^= row&7), complement block
// mapping so co-resident blocks f and f+256 sum to uniform work per CU.
// ---------------------------------------------------------------------------
__global__ __launch_bounds__(256) void attn_kernel(
    const u16* __restrict__ qh, const u16* __restrict__ kh,
    const u16* __restrict__ vT, u16* __restrict__ z) {
  const int f = blockIdx.x;
  const int bh = f & 31;                       // f and f+256 share bh (and CU)
  const int j = f >> 5;
  const int qb = (j < 8) ? (15 - j) : (j - 8); // work(f)+work(f+256) uniform
  const int bb = bh >> 4, hh = bh & 15;
  const int tid = threadIdx.x;
  const int w = tid >> 6, l = tid & 63;
  const int ql = l & 31, hi = l >> 5, hi8 = hi * 8;
  const int q0b = qb * 128;
  const int q0w = q0b + w * 32;

  __shared__ u16 smem[2][2][64][64];  // [buf][K/V][row][64] linear, swizzled

  s16x8 qf[4];
  {
    const u16* qp = qh + ((size_t)bh * NS + q0w + ql) * 64 + hi8;
#pragma unroll
    for (int st = 0; st < 4; ++st) qf[st] = *(const s16x8*)(qp + st * 16);
  }

  f32x16 o0 = {0, 0, 0, 0, 0, 0, 0, 0, 0, 0, 0, 0, 0, 0, 0, 0};
  f32x16 o1 = {0, 0, 0, 0, 0, 0, 0, 0, 0, 0, 0, 0, 0, 0, 0, 0};
  float m_run = -1e30f, l_run = 0.f;

  const int ntiles = (q0b + 128) >> 6;

  // prologue: stage tile 0 -> buf 0
#pragma unroll
  for (int i = 0; i < 2; ++i) {
    int c = i * 256 + tid;
    int row = c >> 3, k8 = (c & 7) ^ (row & 7);
    const u16* sk = kh + ((size_t)bh * NS + row) * 64 + k8 * 8;
    const u16* sv = vT + ((size_t)bh * 64 + row) * NS + k8 * 8;
    u16* dk = &smem[0][0][0][0] + (i * 256 + w * 64) * 8;
    u16* dv = &smem[0][1][0][0] + (i * 256 + w * 64) * 8;
    __builtin_amdgcn_global_load_lds(AS1(sk), AS3(dk), 16, 0, 0);
    __builtin_amdgcn_global_load_lds(AS1(sv), AS3(dv), 16, 0, 0);
  }
  __syncthreads();

  for (int t = 0; t < ntiles; ++t) {
    if (t + 1 < ntiles) {  // stage t+1 into other buffer (overlaps compute)
      int b1 = (t + 1) & 1;
#pragma unroll
      for (int i = 0; i < 2; ++i) {
        int c = i * 256 + tid;
        int row = c >> 3, k8 = (c & 7) ^ (row & 7);
        const u16* sk =
            kh + ((size_t)bh * NS + (t + 1) * 64 + row) * 64 + k8 * 8;
        const u16* sv =
            vT + ((size_t)bh * 64 + row) * NS + (t + 1) * 64 + k8 * 8;
        u16* dk = &smem[b1][0][0][0] + (i * 256 + w * 64) * 8;
        u16* dv = &smem[b1][1][0][0] + (i * 256 + w * 64) * 8;
        __builtin_amdgcn_global_load_lds(AS1(sk), AS3(dk), 16, 0, 0);
        __builtin_amdgcn_global_load_lds(AS1(sv), AS3(dv), 16, 0, 0);
      }
    }
    const u16* kp = &smem[t & 1][0][0][0];
    const u16* vp = &smem[t & 1][1][0][0];

#pragma unroll
    for (int sub = 0; sub < 2; ++sub) {
      const int kvg = t * 64 + sub * 32;
      if (kvg > q0w) continue;
      const bool masked = (kvg == q0w);

      const int kr = sub * 32 + ql;
      f32x16 s = {0, 0, 0, 0, 0, 0, 0, 0, 0, 0, 0, 0, 0, 0, 0, 0};
#pragma unroll
      for (int st = 0; st < 4; ++st) {
        s16x8 ak = *(const s16x8*)(kp + kr * 64 +
                                   (((st * 2 + hi) ^ (kr & 7)) * 8));
        s = __builtin_amdgcn_mfma_f32_32x32x16_bf16(ak, qf[st], s, 0, 0, 0);
      }

      float sv_[16];
#pragma unroll
      for (int r = 0; r < 16; ++r) {
        float x = s[r];
        if (masked) {
          int kvloc = (r & 3) + 8 * (r >> 2) + 4 * hi;
          if (kvloc > ql) x = -1e30f;
        }
        sv_[r] = x;
      }

      float mx = sv_[0];
#pragma unroll
      for (int r = 1; r < 16; ++r) mx = fmaxf(mx, sv_[r]);
      mx = fmaxf(mx, __shfl_xor(mx, 32, 64));

      if (__any(mx > m_run)) {
        float mnew = fmaxf(m_run, mx);
        float fs = __builtin_amdgcn_exp2f(m_run - mnew);
#pragma unroll
        for (int r = 0; r < 16; ++r) {
          o0[r] *= fs;
          o1[r] *= fs;
        }
        l_run *= fs;
        m_run = mnew;
      }

      float ps = 0.f;
      u32 pk[8];
#pragma unroll
      for (int tt = 0; tt < 8; ++tt) {
        float a = __builtin_amdgcn_exp2f(sv_[2 * tt] - m_run);
        float b = __builtin_amdgcn_exp2f(sv_[2 * tt + 1] - m_run);
        ps += a + b;
        pk[tt] = pkbf(a, b);
      }
      ps += __shfl_xor(ps, 32, 64);
      l_run += ps;

      u32 qk[8];
#pragma unroll
      for (int tt = 0; tt < 8; ++tt) qk[tt] = __shfl_xor(pk[tt], 32, 64);

      union { u32 u[4]; s16x8 h; } pf0, pf1;
      pf0.u[0] = hi ? qk[2] : pk[0];
      pf0.u[1] = hi ? qk[3] : pk[1];
      pf0.u[2] = hi ? pk[2] : qk[0];
      pf0.u[3] = hi ? pk[3] : qk[1];
      pf1.u[0] = hi ? qk[6] : pk[4];
      pf1.u[1] = hi ? qk[7] : pk[5];
      pf1.u[2] = hi ? pk[6] : qk[4];
      pf1.u[3] = hi ? pk[7] : qk[5];

#pragma unroll
      for (int k2 = 0; k2 < 2; ++k2) {
        s16x8 pa = (k2 == 0) ? pf0.h : pf1.h;
        int ch = sub * 4 + k2 * 2 + hi;
        s16x8 av0 = *(const s16x8*)(vp + ql * 64 + ((ch ^ (ql & 7)) * 8));
        s16x8 av1 =
            *(const s16x8*)(vp + (32 + ql) * 64 + ((ch ^ (ql & 7)) * 8));
        o0 = __builtin_amdgcn_mfma_f32_32x32x16_bf16(av0, pa, o0, 0, 0, 0);
        o1 = __builtin_amdgcn_mfma_f32_32x32x16_bf16(av1, pa, o1, 0, 0, 0);
      }
    }
    __syncthreads();  // compiler drains vmcnt here -> buf t+1 ready
  }

  // epilogue: per-wave LDS transpose (all compute done after final barrier)
  float inv = 1.f / l_run;
  u16* Zw = &smem[0][0][0][0] + w * (32 * 72);
#pragma unroll
  for (int r = 0; r < 16; r += 2) {
    int d0 = (r & 3) + 8 * (r >> 2) + 4 * hi;
    *(u32*)&Zw[ql * 72 + d0]      = pkbf(o0[r] * inv, o0[r + 1] * inv);
    *(u32*)&Zw[ql * 72 + 32 + d0] = pkbf(o1[r] * inv, o1[r + 1] * inv);
  }
#pragma unroll
  for (int i = 0; i < 4; ++i) {
    int cid = i * 64 + l;
    int row = cid >> 3, c8 = (cid & 7) * 8;
    s16x8 vv = *(const s16x8*)&Zw[row * 72 + c8];
    *(s16x8*)(z + ((size_t)bb * NS + q0w + row) * ND + hh * 64 + c8) = vv;
  }
}

// ---------------------------------------------------------------------------
extern "C" void kernel_launch(void* const* d_in, const int* in_sizes, int n_in,
                              void* d_out, int out_size, void* d_ws,
                              size_t ws_size, hipStream_t stream) {
  const float* Q = (const float*)d_in[0];
  const float* K = (const float*)d_in[1];
  const float* V = (const float*)d_in[2];
  const float* Wq = (const float*)d_in[4];
  const float* bq = (const float*)d_in[5];
  const float* Wk = (const float*)d_in[6];
  const float* bk = (const float*)d_in[7];
  const float* Wv = (const float*)d_in[8];
  const float* bv = (const float*)d_in[9];
  const float* Wo = (const float*)d_in[10];
  const float* bo = (const float*)d_in[11];
  float* out = (float*)d_out;

  const size_t M1 = (size_t)1024 * 1024;  // u16 elements
  u16* base = (u16*)d_ws;

  if (ws_size >= (size_t)58720256) {  // fast path: 56 MB layout
    u16* Wbf = base;             // 4*1M u16
    u16* qh = base + 4 * M1;     // 4M u16 each
    u16* kh = base + 8 * M1;
    u16* vT = base + 12 * M1;
    u16* Xbf = base + 16 * M1;   // 12M u16
    u16* zz = base + 16 * M1;    // aliases Xbf (dead after gemm_qkv)

    cvt_kernel<<<dim3(512, 1, 7), 256, 0, stream>>>(Q, K, V, Wq, Wk, Wv, Wo,
                                                    Xbf, Wbf);
    gemm_qkv_fast<<<dim3(8, 32, 3), 256, 0, stream>>>(Xbf, Wbf, bq, bk, bv, qh,
                                                      kh, vT);
    attn_kernel<<<dim3(512), 256, 0, stream>>>(qh, kh, vT, zz);
    gemm_out_fast<<<dim3(8, 32), 256, 0, stream>>>(zz, Wbf, bo, out);
  } else {  // fallback: 32 MB layout, fp32-input projections
    u16* qh = base;
    u16* kh = base + 4 * M1;
    u16* vT = base + 8 * M1;
    u16* zz = base + 12 * M1;
    proj_qkv_kernel<<<dim3(8, 32, 3), 256, 0, stream>>>(Q, K, V, Wq, bq, Wk,
                                                        bk, Wv, bv, qh, kh, vT);
    attn_kernel<<<dim3(512), 256, 0, stream>>>(qh, kh, vT, zz);
    proj_out_kernel<<<dim3(8, 32), 256, 0, stream>>>(zz, Wo, bo, out);
  }
}